// Round 10
// baseline (422.476 us; speedup 1.0000x reference)
//
#include <hip/hip_runtime.h>
#include <cstddef>

#define NN 10000  // N_NODES

typedef unsigned int u32;
typedef unsigned short u16;
typedef __attribute__((ext_vector_type(8))) short short8;
typedef __attribute__((ext_vector_type(4))) float f32x4;

// ---- bf16 helpers (tables stored bf16, math in f32) ----
__device__ __forceinline__ float bf_lo(u32 v) { union { u32 i; float f; } c; c.i = v << 16; return c.f; }
__device__ __forceinline__ float bf_hi(u32 v) { union { u32 i; float f; } c; c.i = v & 0xFFFF0000u; return c.f; }
__device__ __forceinline__ u32 rne_bits(float f) {
  union { float f; u32 i; } c; c.f = f;
  return c.i + 0x7FFFu + ((c.i >> 16) & 1u);
}
__device__ __forceinline__ u32 pack2(float a, float b) {
  return (rne_bits(a) >> 16) | (rne_bits(b) & 0xFFFF0000u);
}
__device__ __forceinline__ float lrmax(float x) { return fmaxf(x, 0.01f * x); }

// ================= init =================
__global__ __launch_bounds__(256) void wconv_kernel(
    const float* __restrict__ a, const float* __restrict__ b,
    const float* __restrict__ c, const float* __restrict__ d,
    u16* __restrict__ oa, u16* __restrict__ ob,
    u16* __restrict__ oc, u16* __restrict__ od,
    int* __restrict__ degbase) {
  int i = blockIdx.x * 256 + threadIdx.x;
  if (i < 32768) oa[i] = (u16)(rne_bits(a[i]) >> 16);
  else if (i < 98304) ob[i - 32768] = (u16)(rne_bits(b[i - 32768]) >> 16);
  else if (i < 131072) oc[i - 98304] = (u16)(rne_bits(c[i - 98304]) >> 16);
  else if (i < 196608) od[i - 131072] = (u16)(rne_bits(d[i - 131072]) >> 16);
  if (i < 4 * NN) degbase[i] = 0;
}

// ================= CSR =================
__global__ __launch_bounds__(256) void count_b_kernel(const int* __restrict__ dstA,
                                                      const int* __restrict__ dstB,
                                                      int* __restrict__ degbase, int E) {
  const int g = blockIdx.y;
  const int* dst = g ? dstB : dstA;
  int* degi = degbase + (size_t)g * 2 * NN;
  int e = blockIdx.x * 256 + threadIdx.x;
  if (e < E) atomicAdd(&degi[dst[e]], 1);
}

__global__ __launch_bounds__(1024) void scan_b_kernel(const int* __restrict__ degbase,
                                                      int* __restrict__ offbase,
                                                      float* __restrict__ rdegbase, int n) {
  const int g = blockIdx.x;
  const int* degi = degbase + (size_t)g * 2 * NN;
  int* off = offbase + (size_t)g * NN;
  float* rdeg = rdegbase + (size_t)g * NN;
  __shared__ int wsum[16];
  __shared__ int wpre[16];
  __shared__ int carry_s;
  const int tid = threadIdx.x;
  const int lane = tid & 63, w = tid >> 6;
  if (tid == 0) carry_s = 0;
  __syncthreads();
  for (int base = 0; base < n; base += 1024) {
    int i = base + tid;
    int x = (i < n) ? degi[i] : 0;
    int v = x;
#pragma unroll
    for (int d = 1; d < 64; d <<= 1) {
      int t = __shfl_up(v, d);
      if (lane >= d) v += t;
    }
    if (lane == 63) wsum[w] = v;
    __syncthreads();
    if (tid == 0) {
      int s = carry_s;
#pragma unroll
      for (int j = 0; j < 16; ++j) { int t = wsum[j]; wpre[j] = s; s += t; }
      carry_s = s;
    }
    __syncthreads();
    if (i < n) {
      off[i] = wpre[w] + (v - x);
      rdeg[i] = 1.0f / fmaxf((float)x, 1.0f);
    }
    __syncthreads();
  }
}

__global__ __launch_bounds__(256) void fill_b_kernel(const int* __restrict__ srcA,
                                                     const int* __restrict__ dstA,
                                                     const int* __restrict__ srcB,
                                                     const int* __restrict__ dstB,
                                                     const int* __restrict__ offbase,
                                                     int* __restrict__ degbase,
                                                     int* __restrict__ eid_sb,
                                                     int* __restrict__ esrc_sb, int E) {
  const int g = blockIdx.y;
  const int* src = g ? srcB : srcA;
  const int* dst = g ? dstB : dstA;
  const int* off = offbase + (size_t)g * NN;
  int* cursor = degbase + (size_t)g * 2 * NN + NN;
  int* eid_s = eid_sb + (size_t)g * E;
  int* esrc_s = esrc_sb + (size_t)g * E;
  int e = blockIdx.x * 256 + threadIdx.x;
  if (e < E) {
    int d = dst[e];
    int p = off[d] + atomicAdd(&cursor[d], 1);
    eid_s[p] = e;
    esrc_s[p] = src[e];
  }
}

// ================= device stage bodies (single graph, per-node) =================

// A: h[n] = rdeg * segsum(inputs[eid]); half-wave float4
__device__ __forceinline__ void dev_A(int n, int tid, const float* __restrict__ feat,
                                      const int* __restrict__ gidx, const int* __restrict__ off,
                                      const int* __restrict__ degi, const float* __restrict__ rdeg,
                                      u32* __restrict__ outbf) {
  const int lane = tid & 63;
  const int hl = lane & 31, h = lane >> 5;
  const int o = off[n], d = degi[n];
  const int fo = hl << 2;
  float4 acc = make_float4(0.f, 0.f, 0.f, 0.f);
  for (int c0 = 0; c0 < d; c0 += 64) {
    const int m = min(64, d - c0);
    const int gg = (lane < m) ? gidx[o + c0 + lane] : 0;
    const int pairs = m >> 1;
    int i = 0;
    for (; i + 4 <= pairs; i += 4) {
      const int e0 = 2 * i + h;
      const int s0 = __shfl(gg, e0), s1 = __shfl(gg, e0 + 2);
      const int s2 = __shfl(gg, e0 + 4), s3 = __shfl(gg, e0 + 6);
      const float4 v0 = *(const float4*)&feat[(s0 << 7) + fo];
      const float4 v1 = *(const float4*)&feat[(s1 << 7) + fo];
      const float4 v2 = *(const float4*)&feat[(s2 << 7) + fo];
      const float4 v3 = *(const float4*)&feat[(s3 << 7) + fo];
      acc.x += (v0.x + v1.x) + (v2.x + v3.x);
      acc.y += (v0.y + v1.y) + (v2.y + v3.y);
      acc.z += (v0.z + v1.z) + (v2.z + v3.z);
      acc.w += (v0.w + v1.w) + (v2.w + v3.w);
    }
    for (; i < pairs; ++i) {
      const int s0 = __shfl(gg, 2 * i + h);
      const float4 v0 = *(const float4*)&feat[(s0 << 7) + fo];
      acc.x += v0.x; acc.y += v0.y; acc.z += v0.z; acc.w += v0.w;
    }
    if (m & 1) {
      const int s0 = __shfl(gg, m - 1);
      const float wgt = (h == 0) ? 1.f : 0.f;
      const float4 v0 = *(const float4*)&feat[(s0 << 7) + fo];
      acc.x = fmaf(v0.x, wgt, acc.x);
      acc.y = fmaf(v0.y, wgt, acc.y);
      acc.z = fmaf(v0.z, wgt, acc.z);
      acc.w = fmaf(v0.w, wgt, acc.w);
    }
  }
  acc.x += __shfl(acc.x, lane ^ 32);
  acc.y += __shfl(acc.y, lane ^ 32);
  acc.z += __shfl(acc.z, lane ^ 32);
  acc.w += __shfl(acc.w, lane ^ 32);
  if (h == 0) {
    const float sc = rdeg[n];
    uint2 r;
    r.x = pack2(acc.x * sc, acc.y * sc);
    r.y = pack2(acc.z * sc, acc.w * sc);
    *(uint2*)&outbf[(size_t)n * 64 + (hl << 1)] = r;
  }
}

#define QREDUCE8(aL, aH)                                                   \
  aL.x += __shfl(aL.x, lane ^ 16); aL.y += __shfl(aL.y, lane ^ 16);        \
  aL.z += __shfl(aL.z, lane ^ 16); aL.w += __shfl(aL.w, lane ^ 16);        \
  aH.x += __shfl(aH.x, lane ^ 16); aH.y += __shfl(aH.y, lane ^ 16);        \
  aH.z += __shfl(aH.z, lane ^ 16); aH.w += __shfl(aH.w, lane ^ 16);        \
  aL.x += __shfl(aL.x, lane ^ 32); aL.y += __shfl(aL.y, lane ^ 32);        \
  aL.z += __shfl(aL.z, lane ^ 32); aL.w += __shfl(aL.w, lane ^ 32);        \
  aH.x += __shfl(aH.x, lane ^ 32); aH.y += __shfl(aH.y, lane ^ 32);        \
  aH.z += __shfl(aH.z, lane ^ 32); aH.w += __shfl(aH.w, lane ^ 32);

// B: h2[n] = segsum(h[src]); quarter-wave uint4 over 128-feat bf16 rows (256B)
__device__ __forceinline__ void dev_B(int n, int tid, const u32* __restrict__ feat,
                                      const int* __restrict__ gidx, const int* __restrict__ off,
                                      const int* __restrict__ degi, u32* __restrict__ outbf) {
  const int lane = tid & 63;
  const int q = lane >> 4, ql = lane & 15;
  const int o = off[n], d = degi[n];
  const int fo = ql << 2;
  float4 aL = make_float4(0.f, 0.f, 0.f, 0.f), aH = make_float4(0.f, 0.f, 0.f, 0.f);
  for (int c0 = 0; c0 < d; c0 += 64) {
    const int m = min(64, d - c0);
    const int gg = (lane < m) ? gidx[o + c0 + lane] : 0;
    const int full = m >> 2;
    int i = 0;
    for (; i + 2 <= full; i += 2) {
      const int e0 = 4 * i + q;
      const int s0 = __shfl(gg, e0), s1 = __shfl(gg, e0 + 4);
      const uint4 v0 = *(const uint4*)&feat[(s0 << 6) + fo];
      const uint4 v1 = *(const uint4*)&feat[(s1 << 6) + fo];
      aL.x += bf_lo(v0.x) + bf_lo(v1.x); aL.y += bf_hi(v0.x) + bf_hi(v1.x);
      aL.z += bf_lo(v0.y) + bf_lo(v1.y); aL.w += bf_hi(v0.y) + bf_hi(v1.y);
      aH.x += bf_lo(v0.z) + bf_lo(v1.z); aH.y += bf_hi(v0.z) + bf_hi(v1.z);
      aH.z += bf_lo(v0.w) + bf_lo(v1.w); aH.w += bf_hi(v0.w) + bf_hi(v1.w);
    }
    if (i < full) {
      const int s0 = __shfl(gg, 4 * i + q);
      const uint4 v0 = *(const uint4*)&feat[(s0 << 6) + fo];
      aL.x += bf_lo(v0.x); aL.y += bf_hi(v0.x);
      aL.z += bf_lo(v0.y); aL.w += bf_hi(v0.y);
      aH.x += bf_lo(v0.z); aH.y += bf_hi(v0.z);
      aH.z += bf_lo(v0.w); aH.w += bf_hi(v0.w);
    }
    if (m & 3) {
      const int e = (m & ~3) + q;
      const int s0 = __shfl(gg, e < m ? e : (m - 1));
      const float wgt = (e < m) ? 1.f : 0.f;
      const uint4 v0 = *(const uint4*)&feat[(s0 << 6) + fo];
      aL.x = fmaf(bf_lo(v0.x), wgt, aL.x); aL.y = fmaf(bf_hi(v0.x), wgt, aL.y);
      aL.z = fmaf(bf_lo(v0.y), wgt, aL.z); aL.w = fmaf(bf_hi(v0.y), wgt, aL.w);
      aH.x = fmaf(bf_lo(v0.z), wgt, aH.x); aH.y = fmaf(bf_hi(v0.z), wgt, aH.y);
      aH.z = fmaf(bf_lo(v0.w), wgt, aH.z); aH.w = fmaf(bf_hi(v0.w), wgt, aH.w);
    }
  }
  QREDUCE8(aL, aH)
  if (lane < 16) {
    uint4 outv;
    outv.x = pack2(aL.x, aL.y);
    outv.y = pack2(aL.z, aL.w);
    outv.z = pack2(aH.x, aH.y);
    outv.w = pack2(aH.z, aH.w);
    *(uint4*)&outbf[(n << 6) + fo] = outv;
  }
}

__device__ __forceinline__ void acc_lr8(float4& aL, float4& aH, uint4 v,
                                        const float4& wL, const float4& wH) {
  float u;
  u = fmaf(bf_lo(v.x), 0.5f, wL.x); aL.x += lrmax(u);
  u = fmaf(bf_hi(v.x), 0.5f, wL.y); aL.y += lrmax(u);
  u = fmaf(bf_lo(v.y), 0.5f, wL.z); aL.z += lrmax(u);
  u = fmaf(bf_hi(v.y), 0.5f, wL.w); aL.w += lrmax(u);
  u = fmaf(bf_lo(v.z), 0.5f, wH.x); aH.x += lrmax(u);
  u = fmaf(bf_hi(v.z), 0.5f, wH.y); aH.y += lrmax(u);
  u = fmaf(bf_lo(v.w), 0.5f, wH.z); aH.z += lrmax(u);
  u = fmaf(bf_hi(v.w), 0.5f, wH.w); aH.w += lrmax(u);
}
__device__ __forceinline__ void acc_lr8w(float4& aL, float4& aH, uint4 v,
                                         const float4& wL, const float4& wH, float wgt) {
  float u;
  u = fmaf(bf_lo(v.x), 0.5f, wL.x); aL.x = fmaf(lrmax(u), wgt, aL.x);
  u = fmaf(bf_hi(v.x), 0.5f, wL.y); aL.y = fmaf(lrmax(u), wgt, aL.y);
  u = fmaf(bf_lo(v.y), 0.5f, wL.z); aL.z = fmaf(lrmax(u), wgt, aL.z);
  u = fmaf(bf_hi(v.y), 0.5f, wL.w); aL.w = fmaf(lrmax(u), wgt, aL.w);
  u = fmaf(bf_lo(v.z), 0.5f, wH.x); aH.x = fmaf(lrmax(u), wgt, aH.x);
  u = fmaf(bf_hi(v.z), 0.5f, wH.y); aH.y = fmaf(lrmax(u), wgt, aH.y);
  u = fmaf(bf_lo(v.w), 0.5f, wH.z); aH.z = fmaf(lrmax(u), wgt, aH.z);
  u = fmaf(bf_hi(v.w), 0.5f, wH.w); aH.w = fmaf(lrmax(u), wgt, aH.w);
}

// C: hB[n] = rdeg * sum_e LR(0.5*(Z[src]+Z[n])+b); quarter-wave; fh = feature half
__device__ __forceinline__ void dev_C(int n, int fh, int tid, const u32* __restrict__ Z,
                                      const int* __restrict__ esrc, const int* __restrict__ off,
                                      const int* __restrict__ degi, const float* __restrict__ rdeg,
                                      const float* __restrict__ bias, u32* __restrict__ hB) {
  const int lane = tid & 63;
  const int q = lane >> 4, ql = lane & 15;
  const int o = off[n], d = degi[n];
  const int fo = (fh << 6) + (ql << 2);
  const uint4 znv = *(const uint4*)&Z[(n << 7) + fo];
  const float4 bL = *(const float4*)&bias[(fh << 7) + (ql << 3)];
  const float4 bH = *(const float4*)&bias[(fh << 7) + (ql << 3) + 4];
  float4 wL, wH;
  wL.x = fmaf(bf_lo(znv.x), 0.5f, bL.x); wL.y = fmaf(bf_hi(znv.x), 0.5f, bL.y);
  wL.z = fmaf(bf_lo(znv.y), 0.5f, bL.z); wL.w = fmaf(bf_hi(znv.y), 0.5f, bL.w);
  wH.x = fmaf(bf_lo(znv.z), 0.5f, bH.x); wH.y = fmaf(bf_hi(znv.z), 0.5f, bH.y);
  wH.z = fmaf(bf_lo(znv.w), 0.5f, bH.z); wH.w = fmaf(bf_hi(znv.w), 0.5f, bH.w);
  float4 aL = make_float4(0.f, 0.f, 0.f, 0.f), aH = make_float4(0.f, 0.f, 0.f, 0.f);
  for (int c0 = 0; c0 < d; c0 += 64) {
    const int m = min(64, d - c0);
    const int gg = (lane < m) ? esrc[o + c0 + lane] : 0;
    const int full = m >> 2;
    int i = 0;
    for (; i + 2 <= full; i += 2) {
      const int e0 = 4 * i + q;
      const int s0 = __shfl(gg, e0), s1 = __shfl(gg, e0 + 4);
      const uint4 z0 = *(const uint4*)&Z[(s0 << 7) + fo];
      const uint4 z1 = *(const uint4*)&Z[(s1 << 7) + fo];
      acc_lr8(aL, aH, z0, wL, wH);
      acc_lr8(aL, aH, z1, wL, wH);
    }
    if (i < full) {
      const int s0 = __shfl(gg, 4 * i + q);
      const uint4 z0 = *(const uint4*)&Z[(s0 << 7) + fo];
      acc_lr8(aL, aH, z0, wL, wH);
    }
    if (m & 3) {
      const int e = (m & ~3) + q;
      const int s0 = __shfl(gg, e < m ? e : (m - 1));
      const float wgt = (e < m) ? 1.f : 0.f;
      const uint4 z0 = *(const uint4*)&Z[(s0 << 7) + fo];
      acc_lr8w(aL, aH, z0, wL, wH, wgt);
    }
  }
  QREDUCE8(aL, aH)
  if (lane < 16) {
    const float rr = rdeg[n];
    uint4 outv;
    outv.x = pack2(aL.x * rr, aL.y * rr);
    outv.y = pack2(aL.z * rr, aL.w * rr);
    outv.z = pack2(aH.x * rr, aH.y * rr);
    outv.w = pack2(aH.z * rr, aH.w * rr);
    *(uint4*)&hB[(n << 7) + fo] = outv;
  }
}

// C2: h2B[n] = segsum(hB[src]); quarter-wave over 256-feat rows, fh half
__device__ __forceinline__ void dev_C2(int n, int fh, int tid, const u32* __restrict__ feat,
                                       const int* __restrict__ gidx, const int* __restrict__ off,
                                       const int* __restrict__ degi, u32* __restrict__ outbf) {
  const int lane = tid & 63;
  const int q = lane >> 4, ql = lane & 15;
  const int o = off[n], d = degi[n];
  const int fo = (fh << 6) + (ql << 2);
  float4 aL = make_float4(0.f, 0.f, 0.f, 0.f), aH = make_float4(0.f, 0.f, 0.f, 0.f);
  for (int c0 = 0; c0 < d; c0 += 64) {
    const int m = min(64, d - c0);
    const int gg = (lane < m) ? gidx[o + c0 + lane] : 0;
    const int full = m >> 2;
    int i = 0;
    for (; i + 2 <= full; i += 2) {
      const int e0 = 4 * i + q;
      const int s0 = __shfl(gg, e0), s1 = __shfl(gg, e0 + 4);
      const uint4 z0 = *(const uint4*)&feat[(s0 << 7) + fo];
      const uint4 z1 = *(const uint4*)&feat[(s1 << 7) + fo];
      aL.x += bf_lo(z0.x) + bf_lo(z1.x); aL.y += bf_hi(z0.x) + bf_hi(z1.x);
      aL.z += bf_lo(z0.y) + bf_lo(z1.y); aL.w += bf_hi(z0.y) + bf_hi(z1.y);
      aH.x += bf_lo(z0.z) + bf_lo(z1.z); aH.y += bf_hi(z0.z) + bf_hi(z1.z);
      aH.z += bf_lo(z0.w) + bf_lo(z1.w); aH.w += bf_hi(z0.w) + bf_hi(z1.w);
    }
    if (i < full) {
      const int s0 = __shfl(gg, 4 * i + q);
      const uint4 z0 = *(const uint4*)&feat[(s0 << 7) + fo];
      aL.x += bf_lo(z0.x); aL.y += bf_hi(z0.x);
      aL.z += bf_lo(z0.y); aL.w += bf_hi(z0.y);
      aH.x += bf_lo(z0.z); aH.y += bf_hi(z0.z);
      aH.z += bf_lo(z0.w); aH.w += bf_hi(z0.w);
    }
    if (m & 3) {
      const int e = (m & ~3) + q;
      const int s0 = __shfl(gg, e < m ? e : (m - 1));
      const float wgt = (e < m) ? 1.f : 0.f;
      const uint4 z0 = *(const uint4*)&feat[(s0 << 7) + fo];
      aL.x = fmaf(bf_lo(z0.x), wgt, aL.x); aL.y = fmaf(bf_hi(z0.x), wgt, aL.y);
      aL.z = fmaf(bf_lo(z0.y), wgt, aL.z); aL.w = fmaf(bf_hi(z0.y), wgt, aL.w);
      aH.x = fmaf(bf_lo(z0.z), wgt, aH.x); aH.y = fmaf(bf_hi(z0.z), wgt, aH.y);
      aH.z = fmaf(bf_lo(z0.w), wgt, aH.z); aH.w = fmaf(bf_hi(z0.w), wgt, aH.w);
    }
  }
  QREDUCE8(aL, aH)
  if (lane < 16) {
    uint4 outv;
    outv.x = pack2(aL.x, aL.y);
    outv.y = pack2(aL.z, aL.w);
    outv.z = pack2(aH.x, aH.y);
    outv.w = pack2(aH.z, aH.w);
    *(uint4*)&outbf[(n << 7) + fo] = outv;
  }
}

// E: per-block partial sums of LR(0.5*(Z2[src]+Z2[n])+b); blk in [0,128), fh half
__device__ __forceinline__ void dev_E(int blk, int fh, int tid, const u32* __restrict__ Z2,
                                      const int* __restrict__ esrc, const int* __restrict__ off,
                                      const int* __restrict__ degi, const float* __restrict__ bias,
                                      float* __restrict__ partials /* 128 floats out */) {
  const int lane = tid & 63, w = tid >> 6;
  const int q = lane >> 4, ql = lane & 15;
  const int fo = (fh << 6) + (ql << 2);
  const float4 bL = *(const float4*)&bias[(fh << 7) + (ql << 3)];
  const float4 bH = *(const float4*)&bias[(fh << 7) + (ql << 3) + 4];
  float4 aL = make_float4(0.f, 0.f, 0.f, 0.f), aH = make_float4(0.f, 0.f, 0.f, 0.f);
  for (int n = blk * 4 + w; n < NN; n += 512) {
    const int o = off[n], d = degi[n];
    const uint4 znv = *(const uint4*)&Z2[(n << 7) + fo];
    float4 wL, wH;
    wL.x = fmaf(bf_lo(znv.x), 0.5f, bL.x); wL.y = fmaf(bf_hi(znv.x), 0.5f, bL.y);
    wL.z = fmaf(bf_lo(znv.y), 0.5f, bL.z); wL.w = fmaf(bf_hi(znv.y), 0.5f, bL.w);
    wH.x = fmaf(bf_lo(znv.z), 0.5f, bH.x); wH.y = fmaf(bf_hi(znv.z), 0.5f, bH.y);
    wH.z = fmaf(bf_lo(znv.w), 0.5f, bH.z); wH.w = fmaf(bf_hi(znv.w), 0.5f, bH.w);
    for (int c0 = 0; c0 < d; c0 += 64) {
      const int m = min(64, d - c0);
      const int gg = (lane < m) ? esrc[o + c0 + lane] : 0;
      const int full = m >> 2;
      int i = 0;
      for (; i + 2 <= full; i += 2) {
        const int e0 = 4 * i + q;
        const int s0 = __shfl(gg, e0), s1 = __shfl(gg, e0 + 4);
        const uint4 z0 = *(const uint4*)&Z2[(s0 << 7) + fo];
        const uint4 z1 = *(const uint4*)&Z2[(s1 << 7) + fo];
        acc_lr8(aL, aH, z0, wL, wH);
        acc_lr8(aL, aH, z1, wL, wH);
      }
      if (i < full) {
        const int s0 = __shfl(gg, 4 * i + q);
        const uint4 z0 = *(const uint4*)&Z2[(s0 << 7) + fo];
        acc_lr8(aL, aH, z0, wL, wH);
      }
      if (m & 3) {
        const int e = (m & ~3) + q;
        const int s0 = __shfl(gg, e < m ? e : (m - 1));
        const float wgt = (e < m) ? 1.f : 0.f;
        const uint4 z0 = *(const uint4*)&Z2[(s0 << 7) + fo];
        acc_lr8w(aL, aH, z0, wL, wH, wgt);
      }
    }
  }
  QREDUCE8(aL, aH)
  __shared__ float red[4][128];
  if (lane < 16) {
    *(float4*)&red[w][ql << 3] = aL;
    *(float4*)&red[w][(ql << 3) + 4] = aH;
  }
  __syncthreads();
  if (tid < 128) partials[tid] = red[0][tid] + red[1][tid] + red[2][tid] + red[3][tid];
}

// GEMM: C[n][o] = sum_k A[n][k]*W[o][k]; bf16; 64x64 block tile
template <int K>
__device__ __forceinline__ void dev_gemm(int bx, int by, int tid, const u16* __restrict__ A,
                                         const u16* __restrict__ W, u16* __restrict__ C) {
  const int lane = tid & 63;
  const int w = tid >> 6;
  const int wm = w >> 1, wn = w & 1;
  const int bn = bx * 64 + wm * 32;
  const int bo = by * 64 + wn * 32;
  const int r0 = lane & 15;
  const int kq = lane >> 4;
  const int ra0 = min(bn + r0, NN - 1);
  const int ra1 = min(bn + 16 + r0, NN - 1);
  const u16* a0p = &A[(size_t)ra0 * K + kq * 8];
  const u16* a1p = &A[(size_t)ra1 * K + kq * 8];
  const u16* b0p = &W[(size_t)(bo + r0) * K + kq * 8];
  const u16* b1p = &W[(size_t)(bo + 16 + r0) * K + kq * 8];
  f32x4 acc00 = {0.f, 0.f, 0.f, 0.f}, acc01 = {0.f, 0.f, 0.f, 0.f};
  f32x4 acc10 = {0.f, 0.f, 0.f, 0.f}, acc11 = {0.f, 0.f, 0.f, 0.f};
#pragma unroll
  for (int k0 = 0; k0 < K; k0 += 32) {
    const short8 a0 = *(const short8*)(a0p + k0);
    const short8 a1 = *(const short8*)(a1p + k0);
    const short8 b0 = *(const short8*)(b0p + k0);
    const short8 b1 = *(const short8*)(b1p + k0);
    acc00 = __builtin_amdgcn_mfma_f32_16x16x32_bf16(a0, b0, acc00, 0, 0, 0);
    acc01 = __builtin_amdgcn_mfma_f32_16x16x32_bf16(a0, b1, acc01, 0, 0, 0);
    acc10 = __builtin_amdgcn_mfma_f32_16x16x32_bf16(a1, b0, acc10, 0, 0, 0);
    acc11 = __builtin_amdgcn_mfma_f32_16x16x32_bf16(a1, b1, acc11, 0, 0, 0);
  }
#pragma unroll
  for (int r = 0; r < 4; ++r) {
    const int n0 = bn + 4 * kq + r;
    if (n0 < NN) {
      C[(size_t)n0 * 256 + bo + r0] = (u16)(rne_bits(acc00[r]) >> 16);
      C[(size_t)n0 * 256 + bo + 16 + r0] = (u16)(rne_bits(acc01[r]) >> 16);
    }
    const int n1 = bn + 16 + 4 * kq + r;
    if (n1 < NN) {
      C[(size_t)n1 * 256 + bo + r0] = (u16)(rne_bits(acc10[r]) >> 16);
      C[(size_t)n1 * 256 + bo + 16 + r0] = (u16)(rne_bits(acc11[r]) >> 16);
    }
  }
}

// ================= wrapper kernels =================

// plain A for one graph (grid 2500)
__global__ __launch_bounds__(256) void kA_kernel(const float* __restrict__ feat,
                                                 const int* gidx, const int* off,
                                                 const int* degi, const float* rdeg,
                                                 u32* __restrict__ outbf) {
  dev_A((blockIdx.x << 2) + (threadIdx.x >> 6), threadIdx.x, feat, gidx, off, degi, rdeg, outbf);
}

// F1: A-chunk(g1) [625 first] + B(g0) [2500]
__global__ __launch_bounds__(256) void kF_B_A(const u32* featB_, const int* gidxB, const int* offB,
                                              const int* degB, u32* outB,
                                              const float* featA_, const int* gidxA, const int* offA,
                                              const int* degA, const float* rdegA, u32* outA,
                                              int aBase) {
  const int bid = blockIdx.x;
  if (bid < 625) {
    dev_A(aBase + (bid << 2) + (threadIdx.x >> 6), threadIdx.x, featA_, gidxA, offA, degA, rdegA, outA);
  } else {
    dev_B(((bid - 625) << 2) + (threadIdx.x >> 6), threadIdx.x, featB_, gidxB, offB, degB, outB);
  }
}

// F2: A-chunk(g1) [625 first] + GEMM<K>(g0) [628]
template <int K>
__global__ __launch_bounds__(256) void kF_G_A(const u16* Ag, const u16* W, u16* Cg,
                                              const float* featA_, const int* gidxA, const int* offA,
                                              const int* degA, const float* rdegA, u32* outA,
                                              int aBase) {
  const int bid = blockIdx.x;
  if (bid < 625) {
    dev_A(aBase + (bid << 2) + (threadIdx.x >> 6), threadIdx.x, featA_, gidxA, offA, degA, rdegA, outA);
  } else {
    const int gb = bid - 625;
    dev_gemm<K>(gb >> 2, gb & 3, threadIdx.x, Ag, W, Cg);
  }
}

// F3/F4: A-chunk(g1) [625 first] + C or C2 (g0) [5000]
__global__ __launch_bounds__(256) void kF_C_A(const u32* Z, const int* esrc, const int* off,
                                              const int* degi, const float* rdeg, const float* bias,
                                              u32* hB,
                                              const float* featA_, const int* gidxA, const int* offA,
                                              const int* degA, const float* rdegA, u32* outA,
                                              int aBase) {
  const int bid = blockIdx.x;
  if (bid < 625) {
    dev_A(aBase + (bid << 2) + (threadIdx.x >> 6), threadIdx.x, featA_, gidxA, offA, degA, rdegA, outA);
  } else {
    const int cb = bid - 625;
    const int fh = cb >= 2500;
    dev_C(((fh ? cb - 2500 : cb) << 2) + (threadIdx.x >> 6), fh, threadIdx.x, Z, esrc, off, degi,
          rdeg, bias, hB);
  }
}
__global__ __launch_bounds__(256) void kF_C2_A(const u32* feat, const int* gidx, const int* off,
                                               const int* degi, u32* outbf,
                                               const float* featA_, const int* gidxA, const int* offA,
                                               const int* degA, const float* rdegA, u32* outA,
                                               int aBase) {
  const int bid = blockIdx.x;
  if (bid < 625) {
    dev_A(aBase + (bid << 2) + (threadIdx.x >> 6), threadIdx.x, featA_, gidxA, offA, degA, rdegA, outA);
  } else {
    const int cb = bid - 625;
    const int fh = cb >= 2500;
    dev_C2(((fh ? cb - 2500 : cb) << 2) + (threadIdx.x >> 6), fh, threadIdx.x, feat, gidx, off,
           degi, outbf);
  }
}

// F5: B(g1) [2500 first] + GEMM2(g0) [628]
__global__ __launch_bounds__(256) void kF_G2_B(const u16* Ag, const u16* W, u16* Cg,
                                               const u32* featB_, const int* gidxB, const int* offB,
                                               const int* degB, u32* outB) {
  const int bid = blockIdx.x;
  if (bid < 2500) {
    dev_B((bid << 2) + (threadIdx.x >> 6), threadIdx.x, featB_, gidxB, offB, degB, outB);
  } else {
    const int gb = bid - 2500;
    dev_gemm<256>(gb >> 2, gb & 3, threadIdx.x, Ag, W, Cg);
  }
}

// F6: GEMM1(g1) [628 first] + E(g0) [256]
__global__ __launch_bounds__(256) void kF_E_G(const u32* Z2, const int* esrc, const int* off,
                                              const int* degi, const float* bias, float* partials,
                                              const u16* Ag, const u16* W, u16* Cg) {
  const int bid = blockIdx.x;
  if (bid < 628) {
    dev_gemm<128>(bid >> 2, bid & 3, threadIdx.x, Ag, W, Cg);
  } else {
    const int eb = bid - 628;           // [0,256)
    const int fh = eb >> 7, blk = eb & 127;
    dev_E(blk, fh, threadIdx.x, Z2, esrc, off, degi, bias, partials + (size_t)(fh * 128 + blk) * 128);
  }
}

// plain single-graph stages
__global__ __launch_bounds__(256) void kC_kernel(const u32* Z, const int* esrc, const int* off,
                                                 const int* degi, const float* rdeg,
                                                 const float* bias, u32* hB) {
  const int bid = blockIdx.x;
  const int fh = bid >= 2500;
  dev_C(((fh ? bid - 2500 : bid) << 2) + (threadIdx.x >> 6), fh, threadIdx.x, Z, esrc, off, degi,
        rdeg, bias, hB);
}
__global__ __launch_bounds__(256) void kC2_kernel(const u32* feat, const int* gidx, const int* off,
                                                  const int* degi, u32* outbf) {
  const int bid = blockIdx.x;
  const int fh = bid >= 2500;
  dev_C2(((fh ? bid - 2500 : bid) << 2) + (threadIdx.x >> 6), fh, threadIdx.x, feat, gidx, off,
         degi, outbf);
}
__global__ __launch_bounds__(256) void kG_kernel256(const u16* Ag, const u16* W, u16* Cg) {
  dev_gemm<256>(blockIdx.x >> 2, blockIdx.x & 3, threadIdx.x, Ag, W, Cg);
}
__global__ __launch_bounds__(256) void kE_kernel(const u32* Z2, const int* esrc, const int* off,
                                                 const int* degi, const float* bias,
                                                 float* partials) {
  const int fh = blockIdx.x >> 7, blk = blockIdx.x & 127;
  dev_E(blk, fh, threadIdx.x, Z2, esrc, off, degi, bias, partials + (size_t)(fh * 128 + blk) * 128);
}

// final
__global__ __launch_bounds__(1024) void final_fused_kernel(
    const float* __restrict__ partialsb /* [2][2][128][128] */,
    const float* __restrict__ W3, const float* __restrict__ b3,
    float* __restrict__ out, float invE) {
  __shared__ float smacc[512];
  __shared__ float tmp2[2][512];
  __shared__ float red[16][64];
  const int tid = threadIdx.x;
  {
    const int half = tid >> 9;
    const int q = tid & 511;
    const float* basep = partialsb + (size_t)(q >> 7) * 128 * 128 + (q & 127);
    float s = 0.f;
    for (int b = half * 64; b < half * 64 + 64; ++b) s += basep[(size_t)b * 128];
    tmp2[half][q] = s;
  }
  __syncthreads();
  if (tid < 512) smacc[tid] = tmp2[0][tid] + tmp2[1][tid];
  __syncthreads();
  const int j = tid & 63, part = tid >> 6;
  float acc = 0.f;
  for (int kk = 0; kk < 32; ++kk) {
    const int k = part * 32 + kk;
    acc += smacc[k] * W3[(size_t)j * 512 + k];
  }
  red[part][j] = acc;
  __syncthreads();
  if (part == 0) {
    float s = 0.f;
#pragma unroll
    for (int p = 0; p < 16; ++p) s += red[p][j];
    out[j] = b3[j] + s * invE;
  }
}

extern "C" void kernel_launch(void* const* d_in, const int* in_sizes, int n_in,
                              void* d_out, int out_size, void* d_ws, size_t ws_size,
                              hipStream_t stream) {
  const float* in1 = (const float*)d_in[0];
  const int* src1 = (const int*)d_in[1];
  const int* dst1 = (const int*)d_in[2];
  const float* in2 = (const float*)d_in[3];
  const int* src2 = (const int*)d_in[4];
  const int* dst2 = (const int*)d_in[5];
  const float* W11 = (const float*)d_in[6];
  const float* b11 = (const float*)d_in[7];
  const float* W12 = (const float*)d_in[8];
  const float* b12 = (const float*)d_in[9];
  const float* W21 = (const float*)d_in[10];
  const float* b21 = (const float*)d_in[11];
  const float* W22 = (const float*)d_in[12];
  const float* b22 = (const float*)d_in[13];
  const float* W3 = (const float*)d_in[14];
  const float* b3 = (const float*)d_in[15];
  const int E = in_sizes[1];
  const int N = NN;

  char* base = (char*)d_ws;
  size_t pos = 0;
  auto carve = [&](size_t bytes) -> char* {
    char* p = base + pos;
    pos = (pos + bytes + 511) & ~(size_t)511;
    return p;
  };
  int* degbase = (int*)carve((size_t)2 * 2 * N * sizeof(int));
  int* offb = (int*)carve((size_t)2 * N * sizeof(int));
  float* rdegb = (float*)carve((size_t)2 * N * sizeof(float));
  int* eid_sb = (int*)carve((size_t)2 * E * sizeof(int));
  int* esrc_sb = (int*)carve((size_t)2 * E * sizeof(int));
  u32* Hb = (u32*)carve((size_t)2 * N * 64 * sizeof(u32));
  u32* H2b = (u32*)carve((size_t)2 * N * 64 * sizeof(u32));
  u32* Zb = (u32*)carve((size_t)2 * N * 128 * sizeof(u32));
  u32* HBb = (u32*)carve((size_t)2 * N * 128 * sizeof(u32));
  u32* H2Bb = (u32*)carve((size_t)2 * N * 128 * sizeof(u32));
  u16* Wa1 = (u16*)carve((size_t)32768 * sizeof(u16));
  u16* Wb1 = (u16*)carve((size_t)65536 * sizeof(u16));
  u16* Wa2 = (u16*)carve((size_t)32768 * sizeof(u16));
  u16* Wb2 = (u16*)carve((size_t)65536 * sizeof(u16));
  float* partialsb = (float*)carve((size_t)2 * 2 * 128 * 128 * sizeof(float));
  (void)ws_size; (void)n_in; (void)out_size;

  // per-graph pointer sets
  const int* off0 = offb;            const int* off1 = offb + N;
  const int* deg0 = degbase;         const int* deg1 = degbase + 2 * N;
  const float* rdeg0 = rdegb;        const float* rdeg1 = rdegb + N;
  const int* eid0 = eid_sb;          const int* eid1 = eid_sb + E;
  const int* esrc0 = esrc_sb;        const int* esrc1 = esrc_sb + E;
  u32* H0 = Hb;                      u32* H1 = Hb + (size_t)N * 64;
  u32* H20 = H2b;                    u32* H21 = H2b + (size_t)N * 64;
  u32* Z0 = Zb;                      u32* Z1 = Zb + (size_t)N * 128;
  u32* HB0 = HBb;                    u32* HB1 = HBb + (size_t)N * 128;
  u32* H2B0 = H2Bb;                  u32* H2B1 = H2Bb + (size_t)N * 128;
  float* part0 = partialsb;          float* part1 = partialsb + 2 * 128 * 128;

  const int EB = (E + 255) / 256;
  const dim3 g2(EB, 2);

  wconv_kernel<<<768, 256, 0, stream>>>(W11, W12, W21, W22, Wa1, Wb1, Wa2, Wb2, degbase);
  count_b_kernel<<<g2, 256, 0, stream>>>(dst1, dst2, degbase, E);
  scan_b_kernel<<<2, 1024, 0, stream>>>(degbase, offb, rdegb, N);
  fill_b_kernel<<<g2, 256, 0, stream>>>(src1, dst1, src2, dst2, offb, degbase, eid_sb, esrc_sb, E);

  // ---- pipelined schedule: g0 chain, with g1's A chunks / stages fused in ----
  kA_kernel<<<2500, 256, 0, stream>>>(in1, eid0, off0, deg0, rdeg0, H0);                  // A(g0)
  kF_B_A<<<3125, 256, 0, stream>>>(H0, esrc0, off0, deg0, H20,                            // B(g0)
                                   in2, eid1, off1, deg1, rdeg1, H1, 0);                  // +A(g1)c0
  kF_G_A<128><<<1253, 256, 0, stream>>>((const u16*)H20, Wa1, (u16*)Z0,                   // G1(g0)
                                        in2, eid1, off1, deg1, rdeg1, H1, 2500);          // +A(g1)c1
  kF_C_A<<<5625, 256, 0, stream>>>(Z0, esrc0, off0, deg0, rdeg0, b11, HB0,                // C(g0)
                                   in2, eid1, off1, deg1, rdeg1, H1, 5000);               // +A(g1)c2
  kF_C2_A<<<5625, 256, 0, stream>>>(HB0, esrc0, off0, deg0, H2B0,                         // C2(g0)
                                    in2, eid1, off1, deg1, rdeg1, H1, 7500);              // +A(g1)c3
  kF_G2_B<<<3128, 256, 0, stream>>>((const u16*)H2B0, Wb1, (u16*)Z0,                      // G2(g0)
                                    H1, esrc1, off1, deg1, H21);                          // +B(g1)
  kF_E_G<<<884, 256, 0, stream>>>(Z0, esrc0, off0, deg0, b12, part0,                      // E(g0)
                                  (const u16*)H21, Wa2, (u16*)Z1);                        // +G1(g1)
  kC_kernel<<<5000, 256, 0, stream>>>(Z1, esrc1, off1, deg1, rdeg1, b21, HB1);            // C(g1)
  kC2_kernel<<<5000, 256, 0, stream>>>(HB1, esrc1, off1, deg1, H2B1);                     // C2(g1)
  kG_kernel256<<<628, 256, 0, stream>>>((const u16*)H2B1, Wb2, (u16*)Z1);                 // G2(g1)
  kE_kernel<<<256, 256, 0, stream>>>(Z1, esrc1, off1, deg1, b22, part1);                  // E(g1)

  final_fused_kernel<<<1, 1024, 0, stream>>>(partialsb, W3, b3, (float*)d_out, 1.0f / (float)E);
}

// Round 11
// 328.466 us; speedup vs baseline: 1.2862x; 1.2862x over previous
//
#include <hip/hip_runtime.h>
#include <cstddef>

#define NN 10000  // N_NODES
#define NB 2500   // node blocks (4 nodes/block)

typedef unsigned int u32;
typedef unsigned short u16;
typedef __attribute__((ext_vector_type(8))) short short8;
typedef __attribute__((ext_vector_type(4))) float f32x4;

// ---- bf16 helpers (tables stored bf16, math in f32) ----
__device__ __forceinline__ float bf_lo(u32 v) { union { u32 i; float f; } c; c.i = v << 16; return c.f; }
__device__ __forceinline__ float bf_hi(u32 v) { union { u32 i; float f; } c; c.i = v & 0xFFFF0000u; return c.f; }
__device__ __forceinline__ u32 rne_bits(float f) {
  union { float f; u32 i; } c; c.f = f;
  return c.i + 0x7FFFu + ((c.i >> 16) & 1u);
}
__device__ __forceinline__ u32 pack2(float a, float b) {
  return (rne_bits(a) >> 16) | (rne_bits(b) & 0xFFFF0000u);
}
// lrelu(x) = max(x, 0.01x)
__device__ __forceinline__ float lrmax(float x) { return fmaxf(x, 0.01f * x); }

// ---------------- weight convert + workspace zero ----------------
__global__ __launch_bounds__(256) void wconv_kernel(
    const float* __restrict__ a, const float* __restrict__ b,
    const float* __restrict__ c, const float* __restrict__ d,
    u16* __restrict__ oa, u16* __restrict__ ob,
    u16* __restrict__ oc, u16* __restrict__ od,
    int* __restrict__ degbase /* 4*NN ints to zero */) {
  int i = blockIdx.x * 256 + threadIdx.x;  // grid covers 196608
  if (i < 32768) oa[i] = (u16)(rne_bits(a[i]) >> 16);
  else if (i < 98304) ob[i - 32768] = (u16)(rne_bits(b[i - 32768]) >> 16);
  else if (i < 131072) oc[i - 98304] = (u16)(rne_bits(c[i - 98304]) >> 16);
  else if (i < 196608) od[i - 131072] = (u16)(rne_bits(d[i - 131072]) >> 16);
  if (i < 4 * NN) degbase[i] = 0;
}

// ---------------- CSR build (batched over 2 graphs via blockIdx.y) ----------------
__global__ __launch_bounds__(256) void count_b_kernel(const int* __restrict__ dstA,
                                                      const int* __restrict__ dstB,
                                                      int* __restrict__ degbase, int E) {
  const int g = blockIdx.y;
  const int* dst = g ? dstB : dstA;
  int* degi = degbase + (size_t)g * 2 * NN;
  int e = blockIdx.x * 256 + threadIdx.x;
  if (e < E) atomicAdd(&degi[dst[e]], 1);
}

__global__ __launch_bounds__(1024) void scan_b_kernel(const int* __restrict__ degbase,
                                                      int* __restrict__ offbase,
                                                      float* __restrict__ rdegbase, int n) {
  const int g = blockIdx.x;
  const int* degi = degbase + (size_t)g * 2 * NN;
  int* off = offbase + (size_t)g * NN;
  float* rdeg = rdegbase + (size_t)g * NN;
  __shared__ int wsum[16];
  __shared__ int wpre[16];
  __shared__ int carry_s;
  const int tid = threadIdx.x;
  const int lane = tid & 63, w = tid >> 6;
  if (tid == 0) carry_s = 0;
  __syncthreads();
  for (int base = 0; base < n; base += 1024) {
    int i = base + tid;
    int x = (i < n) ? degi[i] : 0;
    int v = x;
#pragma unroll
    for (int d = 1; d < 64; d <<= 1) {
      int t = __shfl_up(v, d);
      if (lane >= d) v += t;
    }
    if (lane == 63) wsum[w] = v;
    __syncthreads();
    if (tid == 0) {
      int s = carry_s;
#pragma unroll
      for (int j = 0; j < 16; ++j) { int t = wsum[j]; wpre[j] = s; s += t; }
      carry_s = s;
    }
    __syncthreads();
    if (i < n) {
      off[i] = wpre[w] + (v - x);              // exclusive prefix
      rdeg[i] = 1.0f / fmaxf((float)x, 1.0f);  // 1/max(deg,1)
    }
    __syncthreads();
  }
}

__global__ __launch_bounds__(256) void fill_b_kernel(const int* __restrict__ srcA,
                                                     const int* __restrict__ dstA,
                                                     const int* __restrict__ srcB,
                                                     const int* __restrict__ dstB,
                                                     const int* __restrict__ offbase,
                                                     int* __restrict__ degbase,
                                                     int* __restrict__ eid_sb,
                                                     int* __restrict__ esrc_sb, int E) {
  const int g = blockIdx.y;
  const int* src = g ? srcB : srcA;
  const int* dst = g ? dstB : dstA;
  const int* off = offbase + (size_t)g * NN;
  int* cursor = degbase + (size_t)g * 2 * NN + NN;
  int* eid_s = eid_sb + (size_t)g * E;
  int* esrc_s = esrc_sb + (size_t)g * E;
  int e = blockIdx.x * 256 + threadIdx.x;
  if (e < E) {
    int d = dst[e];
    int p = off[d] + atomicAdd(&cursor[d], 1);
    eid_s[p] = e;
    esrc_s[p] = src[e];
  }
}

// -------- pass A: h[n] = rdeg * segsum(inputs[eid], dst); f32 in -> bf16 out (128 feats) --------
// half-wave: 32 lanes x float4 = full 512B row; halves take alternate edges; 4 loads in flight.
__global__ __launch_bounds__(256) void gatherA_b_kernel(
    const float* __restrict__ featA, const float* __restrict__ featB,
    const int* __restrict__ gidxb, const int* __restrict__ offbase,
    const int* __restrict__ degbase, const float* __restrict__ rdegbase,
    u32* __restrict__ outbfb /* [2][N*64] */, int E) {
  const int g = blockIdx.y;
  const float* feat = g ? featB : featA;
  const int* gidx = gidxb + (size_t)g * E;
  const int* off = offbase + (size_t)g * NN;
  const int* degi = degbase + (size_t)g * 2 * NN;
  const float* rdeg = rdegbase + (size_t)g * NN;
  u32* outbf = outbfb + (size_t)g * NN * 64;
  const int n = (blockIdx.x << 2) + (threadIdx.x >> 6);
  const int lane = threadIdx.x & 63;
  const int hl = lane & 31, h = lane >> 5;
  const int o = off[n], d = degi[n];
  const int fo = hl << 2;
  float4 acc = make_float4(0.f, 0.f, 0.f, 0.f);
  for (int c0 = 0; c0 < d; c0 += 64) {
    const int m = min(64, d - c0);
    const int gg = (lane < m) ? gidx[o + c0 + lane] : 0;
    const int pairs = m >> 1;  // full pairs: both halves in-range, no guards
    int i = 0;
    for (; i + 4 <= pairs; i += 4) {
      const int e0 = 2 * i + h;
      const int s0 = __shfl(gg, e0), s1 = __shfl(gg, e0 + 2);
      const int s2 = __shfl(gg, e0 + 4), s3 = __shfl(gg, e0 + 6);
      const float4 v0 = *(const float4*)&feat[(s0 << 7) + fo];
      const float4 v1 = *(const float4*)&feat[(s1 << 7) + fo];
      const float4 v2 = *(const float4*)&feat[(s2 << 7) + fo];
      const float4 v3 = *(const float4*)&feat[(s3 << 7) + fo];
      acc.x += (v0.x + v1.x) + (v2.x + v3.x);
      acc.y += (v0.y + v1.y) + (v2.y + v3.y);
      acc.z += (v0.z + v1.z) + (v2.z + v3.z);
      acc.w += (v0.w + v1.w) + (v2.w + v3.w);
    }
    for (; i < pairs; ++i) {
      const int s0 = __shfl(gg, 2 * i + h);
      const float4 v0 = *(const float4*)&feat[(s0 << 7) + fo];
      acc.x += v0.x; acc.y += v0.y; acc.z += v0.z; acc.w += v0.w;
    }
    if (m & 1) {  // odd tail: edge m-1, counted once (half 0)
      const int s0 = __shfl(gg, m - 1);
      const float wgt = (h == 0) ? 1.f : 0.f;
      const float4 v0 = *(const float4*)&feat[(s0 << 7) + fo];
      acc.x = fmaf(v0.x, wgt, acc.x);
      acc.y = fmaf(v0.y, wgt, acc.y);
      acc.z = fmaf(v0.z, wgt, acc.z);
      acc.w = fmaf(v0.w, wgt, acc.w);
    }
  }
  acc.x += __shfl(acc.x, lane ^ 32);
  acc.y += __shfl(acc.y, lane ^ 32);
  acc.z += __shfl(acc.z, lane ^ 32);
  acc.w += __shfl(acc.w, lane ^ 32);
  if (h == 0) {
    const float sc = rdeg[n];
    uint2 r;
    r.x = pack2(acc.x * sc, acc.y * sc);
    r.y = pack2(acc.z * sc, acc.w * sc);
    *(uint2*)&outbf[(size_t)n * 64 + (hl << 1)] = r;
  }
}

// ---- quarter-wave reduce: combine q0..q3 partials; lanes 0-15 end with totals ----
#define QREDUCE8(aL, aH)                                                   \
  aL.x += __shfl(aL.x, lane ^ 16); aL.y += __shfl(aL.y, lane ^ 16);        \
  aL.z += __shfl(aL.z, lane ^ 16); aL.w += __shfl(aL.w, lane ^ 16);        \
  aH.x += __shfl(aH.x, lane ^ 16); aH.y += __shfl(aH.y, lane ^ 16);        \
  aH.z += __shfl(aH.z, lane ^ 16); aH.w += __shfl(aH.w, lane ^ 16);        \
  aL.x += __shfl(aL.x, lane ^ 32); aL.y += __shfl(aL.y, lane ^ 32);        \
  aL.z += __shfl(aL.z, lane ^ 32); aL.w += __shfl(aL.w, lane ^ 32);        \
  aH.x += __shfl(aH.x, lane ^ 32); aH.y += __shfl(aH.y, lane ^ 32);        \
  aH.z += __shfl(aH.z, lane ^ 32); aH.w += __shfl(aH.w, lane ^ 32);

#define SUM8(v)                                                      \
  aL.x += bf_lo(v.x); aL.y += bf_hi(v.x);                            \
  aL.z += bf_lo(v.y); aL.w += bf_hi(v.y);                            \
  aH.x += bf_lo(v.z); aH.y += bf_hi(v.z);                            \
  aH.z += bf_lo(v.w); aH.w += bf_hi(v.w);

// -------- pass B: h2[n] = segsum(h[src]); quarter-wave uint4, 4 edge-groups in flight --------
__global__ __launch_bounds__(256) void gatherB_b_kernel(
    const u32* __restrict__ featb /* [2][N*64] */, const int* __restrict__ gidxb,
    const int* __restrict__ offbase, const int* __restrict__ degbase,
    u32* __restrict__ outbfb, int E) {
  const int bid = blockIdx.x;        // 5000
  const int r = bid & 7, t = bid >> 3;
  const int g = r >> 2;              // XCDs 0-3 -> g0, 4-7 -> g1
  const int nb = t * 4 + (r & 3);    // [0, NB)
  const u32* feat = featb + (size_t)g * NN * 64;
  const int* gidx = gidxb + (size_t)g * E;
  const int* off = offbase + (size_t)g * NN;
  const int* degi = degbase + (size_t)g * 2 * NN;
  u32* outbf = outbfb + (size_t)g * NN * 64;
  const int n = (nb << 2) + (threadIdx.x >> 6);
  const int lane = threadIdx.x & 63;
  const int q = lane >> 4, ql = lane & 15;
  const int o = off[n], d = degi[n];
  const int fo = ql << 2;  // u32 offset (4 u32 = 8 bf16 per lane)
  float4 aL = make_float4(0.f, 0.f, 0.f, 0.f), aH = make_float4(0.f, 0.f, 0.f, 0.f);
  for (int c0 = 0; c0 < d; c0 += 64) {
    const int m = min(64, d - c0);
    const int gg = (lane < m) ? gidx[o + c0 + lane] : 0;
    const int full = m >> 2;
    int i = 0;
    for (; i + 4 <= full; i += 4) {
      const int e0 = 4 * i + q;
      const int s0 = __shfl(gg, e0), s1 = __shfl(gg, e0 + 4);
      const int s2 = __shfl(gg, e0 + 8), s3 = __shfl(gg, e0 + 12);
      const uint4 v0 = *(const uint4*)&feat[(s0 << 6) + fo];
      const uint4 v1 = *(const uint4*)&feat[(s1 << 6) + fo];
      const uint4 v2 = *(const uint4*)&feat[(s2 << 6) + fo];
      const uint4 v3 = *(const uint4*)&feat[(s3 << 6) + fo];
      SUM8(v0) SUM8(v1) SUM8(v2) SUM8(v3)
    }
    for (; i < full; ++i) {
      const int s0 = __shfl(gg, 4 * i + q);
      const uint4 v0 = *(const uint4*)&feat[(s0 << 6) + fo];
      SUM8(v0)
    }
    if (m & 3) {
      const int e = (m & ~3) + q;
      const int s0 = __shfl(gg, e < m ? e : (m - 1));
      const float wgt = (e < m) ? 1.f : 0.f;
      const uint4 v0 = *(const uint4*)&feat[(s0 << 6) + fo];
      aL.x = fmaf(bf_lo(v0.x), wgt, aL.x); aL.y = fmaf(bf_hi(v0.x), wgt, aL.y);
      aL.z = fmaf(bf_lo(v0.y), wgt, aL.z); aL.w = fmaf(bf_hi(v0.y), wgt, aL.w);
      aH.x = fmaf(bf_lo(v0.z), wgt, aH.x); aH.y = fmaf(bf_hi(v0.z), wgt, aH.y);
      aH.z = fmaf(bf_lo(v0.w), wgt, aH.z); aH.w = fmaf(bf_hi(v0.w), wgt, aH.w);
    }
  }
  QREDUCE8(aL, aH)
  if (lane < 16) {
    uint4 outv;
    outv.x = pack2(aL.x, aL.y);
    outv.y = pack2(aL.z, aL.w);
    outv.z = pack2(aH.x, aH.y);
    outv.w = pack2(aH.z, aH.w);
    *(uint4*)&outbf[(n << 6) + fo] = outv;
  }
}

// ---- 8-feat accumulate: acc += lrelu(0.5*z + w), w = 0.5*zn + b hoisted ----
__device__ __forceinline__ void acc_lr8(float4& aL, float4& aH, uint4 v,
                                        const float4& wL, const float4& wH) {
  float u;
  u = fmaf(bf_lo(v.x), 0.5f, wL.x); aL.x += lrmax(u);
  u = fmaf(bf_hi(v.x), 0.5f, wL.y); aL.y += lrmax(u);
  u = fmaf(bf_lo(v.y), 0.5f, wL.z); aL.z += lrmax(u);
  u = fmaf(bf_hi(v.y), 0.5f, wL.w); aL.w += lrmax(u);
  u = fmaf(bf_lo(v.z), 0.5f, wH.x); aH.x += lrmax(u);
  u = fmaf(bf_hi(v.z), 0.5f, wH.y); aH.y += lrmax(u);
  u = fmaf(bf_lo(v.w), 0.5f, wH.z); aH.z += lrmax(u);
  u = fmaf(bf_hi(v.w), 0.5f, wH.w); aH.w += lrmax(u);
}
__device__ __forceinline__ void acc_lr8w(float4& aL, float4& aH, uint4 v,
                                         const float4& wL, const float4& wH, float wgt) {
  float u;
  u = fmaf(bf_lo(v.x), 0.5f, wL.x); aL.x = fmaf(lrmax(u), wgt, aL.x);
  u = fmaf(bf_hi(v.x), 0.5f, wL.y); aL.y = fmaf(lrmax(u), wgt, aL.y);
  u = fmaf(bf_lo(v.y), 0.5f, wL.z); aL.z = fmaf(lrmax(u), wgt, aL.z);
  u = fmaf(bf_hi(v.y), 0.5f, wL.w); aL.w = fmaf(lrmax(u), wgt, aL.w);
  u = fmaf(bf_lo(v.z), 0.5f, wH.x); aH.x = fmaf(lrmax(u), wgt, aH.x);
  u = fmaf(bf_hi(v.z), 0.5f, wH.y); aH.y = fmaf(lrmax(u), wgt, aH.y);
  u = fmaf(bf_lo(v.w), 0.5f, wH.z); aH.z = fmaf(lrmax(u), wgt, aH.z);
  u = fmaf(bf_hi(v.w), 0.5f, wH.w); aH.w = fmaf(lrmax(u), wgt, aH.w);
}

// -------- pass C: hB[n] = rdeg * sum_e LR(0.5*(Z[src]+Z[n])+b); quarter-wave, fh swizzle --------
__global__ __launch_bounds__(256) void passC_b_kernel(
    const u32* __restrict__ Zb_, const int* __restrict__ esrcb,
    const int* __restrict__ offbase, const int* __restrict__ degbase,
    const float* __restrict__ rdegbase,
    const float* __restrict__ biasA, const float* __restrict__ biasB,
    u32* __restrict__ hBb, int E) {
  const int bid = blockIdx.x;  // 10000
  const int r = bid & 7, t = bid >> 3;
  const int g = r >> 2, fh = (r >> 1) & 1;
  const int nb = t * 2 + (r & 1);
  const u32* Z = Zb_ + (size_t)g * NN * 128;
  const int* esrc = esrcb + (size_t)g * E;
  const int* off = offbase + (size_t)g * NN;
  const int* degi = degbase + (size_t)g * 2 * NN;
  const float* rdeg = rdegbase + (size_t)g * NN;
  const float* bias = g ? biasB : biasA;
  u32* hB = hBb + (size_t)g * NN * 128;
  const int n = (nb << 2) + (threadIdx.x >> 6);
  const int lane = threadIdx.x & 63;
  const int q = lane >> 4, ql = lane & 15;
  const int o = off[n], d = degi[n];
  const int fo = (fh << 6) + (ql << 2);
  const uint4 znv = *(const uint4*)&Z[(n << 7) + fo];
  const float4 bL = *(const float4*)&bias[(fh << 7) + (ql << 3)];
  const float4 bH = *(const float4*)&bias[(fh << 7) + (ql << 3) + 4];
  float4 wL, wH;
  wL.x = fmaf(bf_lo(znv.x), 0.5f, bL.x); wL.y = fmaf(bf_hi(znv.x), 0.5f, bL.y);
  wL.z = fmaf(bf_lo(znv.y), 0.5f, bL.z); wL.w = fmaf(bf_hi(znv.y), 0.5f, bL.w);
  wH.x = fmaf(bf_lo(znv.z), 0.5f, bH.x); wH.y = fmaf(bf_hi(znv.z), 0.5f, bH.y);
  wH.z = fmaf(bf_lo(znv.w), 0.5f, bH.z); wH.w = fmaf(bf_hi(znv.w), 0.5f, bH.w);
  float4 aL = make_float4(0.f, 0.f, 0.f, 0.f), aH = make_float4(0.f, 0.f, 0.f, 0.f);
  for (int c0 = 0; c0 < d; c0 += 64) {
    const int m = min(64, d - c0);
    const int gg = (lane < m) ? esrc[o + c0 + lane] : 0;
    const int full = m >> 2;
    int i = 0;
    for (; i + 4 <= full; i += 4) {
      const int e0 = 4 * i + q;
      const int s0 = __shfl(gg, e0), s1 = __shfl(gg, e0 + 4);
      const int s2 = __shfl(gg, e0 + 8), s3 = __shfl(gg, e0 + 12);
      const uint4 z0 = *(const uint4*)&Z[(s0 << 7) + fo];
      const uint4 z1 = *(const uint4*)&Z[(s1 << 7) + fo];
      const uint4 z2 = *(const uint4*)&Z[(s2 << 7) + fo];
      const uint4 z3 = *(const uint4*)&Z[(s3 << 7) + fo];
      acc_lr8(aL, aH, z0, wL, wH);
      acc_lr8(aL, aH, z1, wL, wH);
      acc_lr8(aL, aH, z2, wL, wH);
      acc_lr8(aL, aH, z3, wL, wH);
    }
    for (; i < full; ++i) {
      const int s0 = __shfl(gg, 4 * i + q);
      const uint4 z0 = *(const uint4*)&Z[(s0 << 7) + fo];
      acc_lr8(aL, aH, z0, wL, wH);
    }
    if (m & 3) {
      const int e = (m & ~3) + q;
      const int s0 = __shfl(gg, e < m ? e : (m - 1));
      const float wgt = (e < m) ? 1.f : 0.f;
      const uint4 z0 = *(const uint4*)&Z[(s0 << 7) + fo];
      acc_lr8w(aL, aH, z0, wL, wH, wgt);
    }
  }
  QREDUCE8(aL, aH)
  if (lane < 16) {
    const float rr = rdeg[n];
    uint4 outv;
    outv.x = pack2(aL.x * rr, aL.y * rr);
    outv.y = pack2(aL.z * rr, aL.w * rr);
    outv.z = pack2(aH.x * rr, aH.y * rr);
    outv.w = pack2(aH.z * rr, aH.w * rr);
    *(uint4*)&hB[(n << 7) + fo] = outv;
  }
}

// -------- gather C: h2B[n] = segsum(hB[src]); quarter-wave, fh swizzle --------
__global__ __launch_bounds__(256) void gatherC_b_kernel(
    const u32* __restrict__ featb /* [2][N*128] */, const int* __restrict__ gidxb,
    const int* __restrict__ offbase, const int* __restrict__ degbase,
    u32* __restrict__ outbfb, int E) {
  const int bid = blockIdx.x;  // 10000
  const int r = bid & 7, t = bid >> 3;
  const int g = r >> 2, fh = (r >> 1) & 1;
  const int nb = t * 2 + (r & 1);
  const u32* feat = featb + (size_t)g * NN * 128;
  const int* gidx = gidxb + (size_t)g * E;
  const int* off = offbase + (size_t)g * NN;
  const int* degi = degbase + (size_t)g * 2 * NN;
  u32* outbf = outbfb + (size_t)g * NN * 128;
  const int n = (nb << 2) + (threadIdx.x >> 6);
  const int lane = threadIdx.x & 63;
  const int q = lane >> 4, ql = lane & 15;
  const int o = off[n], d = degi[n];
  const int fo = (fh << 6) + (ql << 2);
  float4 aL = make_float4(0.f, 0.f, 0.f, 0.f), aH = make_float4(0.f, 0.f, 0.f, 0.f);
  for (int c0 = 0; c0 < d; c0 += 64) {
    const int m = min(64, d - c0);
    const int gg = (lane < m) ? gidx[o + c0 + lane] : 0;
    const int full = m >> 2;
    int i = 0;
    for (; i + 4 <= full; i += 4) {
      const int e0 = 4 * i + q;
      const int s0 = __shfl(gg, e0), s1 = __shfl(gg, e0 + 4);
      const int s2 = __shfl(gg, e0 + 8), s3 = __shfl(gg, e0 + 12);
      const uint4 z0 = *(const uint4*)&feat[(s0 << 7) + fo];
      const uint4 z1 = *(const uint4*)&feat[(s1 << 7) + fo];
      const uint4 z2 = *(const uint4*)&feat[(s2 << 7) + fo];
      const uint4 z3 = *(const uint4*)&feat[(s3 << 7) + fo];
      SUM8(z0) SUM8(z1) SUM8(z2) SUM8(z3)
    }
    for (; i < full; ++i) {
      const int s0 = __shfl(gg, 4 * i + q);
      const uint4 z0 = *(const uint4*)&feat[(s0 << 7) + fo];
      SUM8(z0)
    }
    if (m & 3) {
      const int e = (m & ~3) + q;
      const int s0 = __shfl(gg, e < m ? e : (m - 1));
      const float wgt = (e < m) ? 1.f : 0.f;
      const uint4 z0 = *(const uint4*)&feat[(s0 << 7) + fo];
      aL.x = fmaf(bf_lo(z0.x), wgt, aL.x); aL.y = fmaf(bf_hi(z0.x), wgt, aL.y);
      aL.z = fmaf(bf_lo(z0.y), wgt, aL.z); aL.w = fmaf(bf_hi(z0.y), wgt, aL.w);
      aH.x = fmaf(bf_lo(z0.z), wgt, aH.x); aH.y = fmaf(bf_hi(z0.z), wgt, aH.y);
      aH.z = fmaf(bf_lo(z0.w), wgt, aH.z); aH.w = fmaf(bf_hi(z0.w), wgt, aH.w);
    }
  }
  QREDUCE8(aL, aH)
  if (lane < 16) {
    uint4 outv;
    outv.x = pack2(aL.x, aL.y);
    outv.y = pack2(aL.z, aL.w);
    outv.z = pack2(aH.x, aH.y);
    outv.w = pack2(aH.z, aH.w);
    *(uint4*)&outbf[(n << 7) + fo] = outv;
  }
}

// -------- pass E: partial sums of LR(0.5*(Z2[src]+Z2[n])+b); quarter-wave, fh swizzle --------
__global__ __launch_bounds__(256) void passE_b_kernel(
    const u32* __restrict__ Z2b, const int* __restrict__ esrcb,
    const int* __restrict__ offbase, const int* __restrict__ degbase,
    const float* __restrict__ biasA, const float* __restrict__ biasB,
    float* __restrict__ partialsb /* [2][2][128][128] */, int nNodes, int E) {
  const int bid = blockIdx.x;  // 512
  const int r = bid & 7, t = bid >> 3;  // t < 64
  const int g = r >> 2, fh = (r >> 1) & 1;
  const int blk = t * 2 + (r & 1);      // [0,128) within combo
  const u32* Z2 = Z2b + (size_t)g * NN * 128;
  const int* esrc = esrcb + (size_t)g * E;
  const int* off = offbase + (size_t)g * NN;
  const int* degi = degbase + (size_t)g * 2 * NN;
  const float* bias = g ? biasB : biasA;
  float* partials = partialsb + (size_t)((g * 2 + fh) * 128 + blk) * 128;
  const int lane = threadIdx.x & 63, w = threadIdx.x >> 6;
  const int q = lane >> 4, ql = lane & 15;
  const int fo = (fh << 6) + (ql << 2);
  const float4 bL = *(const float4*)&bias[(fh << 7) + (ql << 3)];
  const float4 bH = *(const float4*)&bias[(fh << 7) + (ql << 3) + 4];
  float4 aL = make_float4(0.f, 0.f, 0.f, 0.f), aH = make_float4(0.f, 0.f, 0.f, 0.f);
  for (int n = blk * 4 + w; n < nNodes; n += 512) {
    const int o = off[n], d = degi[n];
    const uint4 znv = *(const uint4*)&Z2[(n << 7) + fo];
    float4 wL, wH;
    wL.x = fmaf(bf_lo(znv.x), 0.5f, bL.x); wL.y = fmaf(bf_hi(znv.x), 0.5f, bL.y);
    wL.z = fmaf(bf_lo(znv.y), 0.5f, bL.z); wL.w = fmaf(bf_hi(znv.y), 0.5f, bL.w);
    wH.x = fmaf(bf_lo(znv.z), 0.5f, bH.x); wH.y = fmaf(bf_hi(znv.z), 0.5f, bH.y);
    wH.z = fmaf(bf_lo(znv.w), 0.5f, bH.z); wH.w = fmaf(bf_hi(znv.w), 0.5f, bH.w);
    for (int c0 = 0; c0 < d; c0 += 64) {
      const int m = min(64, d - c0);
      const int gg = (lane < m) ? esrc[o + c0 + lane] : 0;
      const int full = m >> 2;
      int i = 0;
      for (; i + 4 <= full; i += 4) {
        const int e0 = 4 * i + q;
        const int s0 = __shfl(gg, e0), s1 = __shfl(gg, e0 + 4);
        const int s2 = __shfl(gg, e0 + 8), s3 = __shfl(gg, e0 + 12);
        const uint4 z0 = *(const uint4*)&Z2[(s0 << 7) + fo];
        const uint4 z1 = *(const uint4*)&Z2[(s1 << 7) + fo];
        const uint4 z2 = *(const uint4*)&Z2[(s2 << 7) + fo];
        const uint4 z3 = *(const uint4*)&Z2[(s3 << 7) + fo];
        acc_lr8(aL, aH, z0, wL, wH);
        acc_lr8(aL, aH, z1, wL, wH);
        acc_lr8(aL, aH, z2, wL, wH);
        acc_lr8(aL, aH, z3, wL, wH);
      }
      for (; i < full; ++i) {
        const int s0 = __shfl(gg, 4 * i + q);
        const uint4 z0 = *(const uint4*)&Z2[(s0 << 7) + fo];
        acc_lr8(aL, aH, z0, wL, wH);
      }
      if (m & 3) {
        const int e = (m & ~3) + q;
        const int s0 = __shfl(gg, e < m ? e : (m - 1));
        const float wgt = (e < m) ? 1.f : 0.f;
        const uint4 z0 = *(const uint4*)&Z2[(s0 << 7) + fo];
        acc_lr8w(aL, aH, z0, wL, wH, wgt);
      }
    }
  }
  QREDUCE8(aL, aH)
  __shared__ float red[4][128];
  if (lane < 16) {
    *(float4*)&red[w][ql << 3] = aL;
    *(float4*)&red[w][(ql << 3) + 4] = aH;
  }
  __syncthreads();
  const int tid = threadIdx.x;
  if (tid < 128) partials[tid] = red[0][tid] + red[1][tid] + red[2][tid] + red[3][tid];
}

// -------- fused reduce + final: out[j] = b3[j] + invE * sum_k macc[k] * W3[j][k] --------
__global__ __launch_bounds__(1024) void final_fused_kernel(
    const float* __restrict__ partialsb /* [2][2][128][128] */,
    const float* __restrict__ W3, const float* __restrict__ b3,
    float* __restrict__ out, float invE) {
  __shared__ float smacc[512];  // index k = g*256 + fh*128 + j
  __shared__ float tmp2[2][512];
  __shared__ float red[16][64];
  const int tid = threadIdx.x;
  {
    const int half = tid >> 9;   // 0,1
    const int q = tid & 511;     // = g*256 + fh*128 + j
    const float* basep = partialsb + (size_t)(q >> 7) * 128 * 128 + (q & 127);
    float s = 0.f;
    for (int b = half * 64; b < half * 64 + 64; ++b) s += basep[(size_t)b * 128];
    tmp2[half][q] = s;
  }
  __syncthreads();
  if (tid < 512) smacc[tid] = tmp2[0][tid] + tmp2[1][tid];
  __syncthreads();
  const int j = tid & 63, part = tid >> 6;
  float acc = 0.f;
  for (int kk = 0; kk < 32; ++kk) {
    const int k = part * 32 + kk;
    acc += smacc[k] * W3[(size_t)j * 512 + k];
  }
  red[part][j] = acc;
  __syncthreads();
  if (part == 0) {
    float s = 0.f;
#pragma unroll
    for (int p = 0; p < 16; ++p) s += red[p][j];
    out[j] = b3[j] + s * invE;
  }
}

// -------- MFMA GEMM: C[n][o] = sum_k A[n][k]*W[o][k]; A,W,C bf16; O=256; batched via z --------
template <int K>
__global__ __launch_bounds__(256) void gemm_mfma_b_kernel(const u16* __restrict__ Ab,
                                                          const u16* __restrict__ WA,
                                                          const u16* __restrict__ WB,
                                                          u16* __restrict__ Cb, int N) {
  const int g = blockIdx.z;
  const u16* A = Ab + (size_t)g * NN * K;
  const u16* Wb = g ? WB : WA;
  u16* C = Cb + (size_t)g * NN * 256;
  const int lane = threadIdx.x & 63;
  const int w = threadIdx.x >> 6;
  const int wm = w >> 1, wn = w & 1;
  const int bn = blockIdx.x * 64 + wm * 32;
  const int bo = blockIdx.y * 64 + wn * 32;
  const int r0 = lane & 15;  // A-row / B-col within 16-tile
  const int kq = lane >> 4;  // k-quarter: 8 elems each
  const int ra0 = min(bn + r0, N - 1);
  const int ra1 = min(bn + 16 + r0, N - 1);
  const u16* a0p = &A[(size_t)ra0 * K + kq * 8];
  const u16* a1p = &A[(size_t)ra1 * K + kq * 8];
  const u16* b0p = &Wb[(size_t)(bo + r0) * K + kq * 8];
  const u16* b1p = &Wb[(size_t)(bo + 16 + r0) * K + kq * 8];
  f32x4 acc00 = {0.f, 0.f, 0.f, 0.f}, acc01 = {0.f, 0.f, 0.f, 0.f};
  f32x4 acc10 = {0.f, 0.f, 0.f, 0.f}, acc11 = {0.f, 0.f, 0.f, 0.f};
#pragma unroll
  for (int k0 = 0; k0 < K; k0 += 32) {
    const short8 a0 = *(const short8*)(a0p + k0);
    const short8 a1 = *(const short8*)(a1p + k0);
    const short8 b0 = *(const short8*)(b0p + k0);
    const short8 b1 = *(const short8*)(b1p + k0);
    acc00 = __builtin_amdgcn_mfma_f32_16x16x32_bf16(a0, b0, acc00, 0, 0, 0);
    acc01 = __builtin_amdgcn_mfma_f32_16x16x32_bf16(a0, b1, acc01, 0, 0, 0);
    acc10 = __builtin_amdgcn_mfma_f32_16x16x32_bf16(a1, b0, acc10, 0, 0, 0);
    acc11 = __builtin_amdgcn_mfma_f32_16x16x32_bf16(a1, b1, acc11, 0, 0, 0);
  }
  // D layout: row = 4*kq + r (within 16-tile), col = r0
#pragma unroll
  for (int r = 0; r < 4; ++r) {
    const int n0 = bn + 4 * kq + r;
    if (n0 < N) {
      C[(size_t)n0 * 256 + bo + r0] = (u16)(rne_bits(acc00[r]) >> 16);
      C[(size_t)n0 * 256 + bo + 16 + r0] = (u16)(rne_bits(acc01[r]) >> 16);
    }
    const int n1 = bn + 16 + 4 * kq + r;
    if (n1 < N) {
      C[(size_t)n1 * 256 + bo + r0] = (u16)(rne_bits(acc10[r]) >> 16);
      C[(size_t)n1 * 256 + bo + 16 + r0] = (u16)(rne_bits(acc11[r]) >> 16);
    }
  }
}

extern "C" void kernel_launch(void* const* d_in, const int* in_sizes, int n_in,
                              void* d_out, int out_size, void* d_ws, size_t ws_size,
                              hipStream_t stream) {
  const float* in1 = (const float*)d_in[0];
  const int* src1 = (const int*)d_in[1];
  const int* dst1 = (const int*)d_in[2];
  const float* in2 = (const float*)d_in[3];
  const int* src2 = (const int*)d_in[4];
  const int* dst2 = (const int*)d_in[5];
  const float* W11 = (const float*)d_in[6];
  const float* b11 = (const float*)d_in[7];
  const float* W12 = (const float*)d_in[8];
  const float* b12 = (const float*)d_in[9];
  const float* W21 = (const float*)d_in[10];
  const float* b21 = (const float*)d_in[11];
  const float* W22 = (const float*)d_in[12];
  const float* b22 = (const float*)d_in[13];
  const float* W3 = (const float*)d_in[14];
  const float* b3 = (const float*)d_in[15];
  const int E = in_sizes[1];
  const int N = NN;

  // ---- workspace carve (512B aligned) ----
  char* base = (char*)d_ws;
  size_t pos = 0;
  auto carve = [&](size_t bytes) -> char* {
    char* p = base + pos;
    pos = (pos + bytes + 511) & ~(size_t)511;
    return p;
  };
  int* degbase = (int*)carve((size_t)2 * 2 * N * sizeof(int));  // [g][deg|cursor]
  int* offb = (int*)carve((size_t)2 * N * sizeof(int));
  float* rdegb = (float*)carve((size_t)2 * N * sizeof(float));
  int* eid_sb = (int*)carve((size_t)2 * E * sizeof(int));
  int* esrc_sb = (int*)carve((size_t)2 * E * sizeof(int));
  u32* Hb = (u32*)carve((size_t)2 * N * 64 * sizeof(u32));     // h   (bf16, 128 feats)
  u32* H2b = (u32*)carve((size_t)2 * N * 64 * sizeof(u32));    // h2  (bf16, 128 feats)
  u32* Zb = (u32*)carve((size_t)2 * N * 128 * sizeof(u32));    // Z / Z2 (bf16, 256 feats)
  u32* HBb = (u32*)carve((size_t)2 * N * 128 * sizeof(u32));   // hB  (bf16, 256 feats)
  u32* H2Bb = (u32*)carve((size_t)2 * N * 128 * sizeof(u32));  // h2B (bf16, 256 feats)
  u16* Wa1 = (u16*)carve((size_t)32768 * sizeof(u16));         // W11 bf16
  u16* Wb1 = (u16*)carve((size_t)65536 * sizeof(u16));         // W12 bf16
  u16* Wa2 = (u16*)carve((size_t)32768 * sizeof(u16));         // W21 bf16
  u16* Wb2 = (u16*)carve((size_t)65536 * sizeof(u16));         // W22 bf16
  float* partialsb = (float*)carve((size_t)2 * 2 * 128 * 128 * sizeof(float));
  (void)ws_size; (void)n_in; (void)out_size;

  const int EB = (E + 255) / 256;
  const dim3 g2(EB, 2);
  const dim3 n2(NB, 2);
  const dim3 gemm_grid((N + 63) / 64, 4, 2);

  wconv_kernel<<<768, 256, 0, stream>>>(W11, W12, W21, W22, Wa1, Wb1, Wa2, Wb2, degbase);

  count_b_kernel<<<g2, 256, 0, stream>>>(dst1, dst2, degbase, E);
  scan_b_kernel<<<2, 1024, 0, stream>>>(degbase, offb, rdegb, N);
  fill_b_kernel<<<g2, 256, 0, stream>>>(src1, dst1, src2, dst2, offb, degbase, eid_sb, esrc_sb, E);

  // layer 1: h = segsum(inputs, dst)/deg ; h2 = segsum(h[src], dst) ; Z = h2 @ Wa.T
  gatherA_b_kernel<<<n2, 256, 0, stream>>>(in1, in2, eid_sb, offb, degbase, rdegb, Hb, E);
  gatherB_b_kernel<<<2 * NB, 256, 0, stream>>>(Hb, esrc_sb, offb, degbase, H2b, E);
  gemm_mfma_b_kernel<128><<<gemm_grid, 256, 0, stream>>>((const u16*)H2b, Wa1, Wa2, (u16*)Zb, N);

  // layer 2 input: hB = rdeg * segsum(LR(0.5*(Z[src]+Z[dst])+ba), dst)
  passC_b_kernel<<<4 * NB, 256, 0, stream>>>(Zb, esrc_sb, offb, degbase, rdegb, b11, b21, HBb, E);
  // h2B = segsum(hB[src], dst) ; Z2 = h2B @ Wb.T
  gatherC_b_kernel<<<4 * NB, 256, 0, stream>>>(HBb, esrc_sb, offb, degbase, H2Bb, E);
  gemm_mfma_b_kernel<256><<<gemm_grid, 256, 0, stream>>>((const u16*)H2Bb, Wb1, Wb2, (u16*)Zb, N);

  // mean over edges of LR(0.5*(Z2[src]+Z2[dst])+bb)
  passE_b_kernel<<<512, 256, 0, stream>>>(Zb, esrc_sb, offb, degbase, b12, b22, partialsb, N, E);
  final_fused_kernel<<<1, 1024, 0, stream>>>(partialsb, W3, b3, (float*)d_out, 1.0f / (float)E);
}